// Round 4
// baseline (130.207 us; speedup 1.0000x reference)
//
#include <hip/hip_runtime.h>

#define EDIM 1280
#define BDIM 64
#define HDIM 20
#define PDIM 448
#define DDIM 64
#define NCOL 3840      // 3*EDIM (q,k,v columns fused)
#define NCHUNK 4
#define ECHUNK 320     // EDIM / NCHUNK
#define CTILE 32       // columns per block
#define NTILE 7        // 448 / 64 key tiles

__device__ __forceinline__ float dot4(float4 a, float4 b) {
    return a.x * b.x + a.y * b.y + a.z * b.z + a.w * b.w;
}

// async global->LDS DMA: 16B per lane, LDS dest = wave-uniform base + lane*16
__device__ __forceinline__ void dma16(const float* g, float* l) {
    __builtin_amdgcn_global_load_lds(
        (const __attribute__((address_space(1))) void*)(g),
        (__attribute__((address_space(3))) void*)(l),
        16, 0, 0);
}

// stage one 64x64-float K tile (16 KB): 4 DMA instrs per wave
__device__ __forceinline__ void dma_tile(const float* tbase, float* lbase,
                                         int w, int lane) {
#pragma unroll
    for (int r = 0; r < 4; ++r) {
        dma16(tbase + (size_t)(r * 256 + w * 64 + lane) * 4,
              lbase + (r * 256 + w * 64) * 4);
    }
}

// ---------------------------------------------------------------------------
// Kernel 1: fused QKV projection, LDS-staged weights.
// ---------------------------------------------------------------------------
__global__ __launch_bounds__(256) void proj_qkv(
    const float* __restrict__ h,
    const float* __restrict__ Wq, const float* __restrict__ Wk,
    const float* __restrict__ Wv,
    float* __restrict__ partial)
{
    __shared__ float Wt[CTILE * ECHUNK];   // 40 KB

    const int wave = threadIdx.x >> 6;
    const int lane = threadIdx.x & 63;
    const int colbase = blockIdx.x * CTILE;
    const int e0 = blockIdx.y * ECHUNK;

    const float* W; int wc;
    if (colbase < EDIM)          { W = Wq; wc = colbase; }
    else if (colbase < 2 * EDIM) { W = Wk; wc = colbase - EDIM; }
    else                         { W = Wv; wc = colbase - 2 * EDIM; }

#pragma unroll
    for (int i = 0; i < 10; ++i) {
        int i4 = (i * 256 + threadIdx.x) * 4;
        int c  = i4 / ECHUNK;
        int e  = i4 - c * ECHUNK;
        *reinterpret_cast<float4*>(&Wt[i4]) =
            *reinterpret_cast<const float4*>(&W[(size_t)(wc + c) * EDIM + e0 + e]);
    }
    __syncthreads();

    float acc[8];
#pragma unroll
    for (int c = 0; c < 8; ++c) acc[c] = 0.f;

    const float4* hp = reinterpret_cast<const float4*>(h + lane * EDIM + e0);
    const int c0 = wave * 8;
#pragma unroll 4
    for (int eg = 0; eg < ECHUNK / 4; ++eg) {
        float4 hv = hp[eg];
#pragma unroll
        for (int c = 0; c < 8; ++c) {
            float4 wv = *reinterpret_cast<const float4*>(&Wt[(c0 + c) * ECHUNK + eg * 4]);
            acc[c] += dot4(hv, wv);
        }
    }
#pragma unroll
    for (int c = 0; c < 8; ++c)
        partial[((size_t)blockIdx.y * NCOL + colbase + c0 + c) * 64 + lane] = acc[c];
}

// ---------------------------------------------------------------------------
// Kernel 2: reduce QKV partials.
// ---------------------------------------------------------------------------
__global__ __launch_bounds__(256) void reduce_proj(
    const float* __restrict__ partial,
    const float* __restrict__ bq, const float* __restrict__ bv,
    float* __restrict__ qout, float* __restrict__ kout, float* __restrict__ vout)
{
    __shared__ float tile[256];
    const int cg0 = blockIdx.x * 4;
    const int idx = cg0 * 64 + threadIdx.x;
    float v = partial[idx] + partial[245760 + idx]
            + partial[491520 + idx] + partial[737280 + idx];
    tile[threadIdx.x] = v;
    __syncthreads();
    const int row = threadIdx.x >> 2;
    const int c   = threadIdx.x & 3;
    const int cg  = cg0 + c;
    const float v2 = tile[c * 64 + row];
    if (cg < EDIM)
        qout[row * EDIM + cg] = (v2 + bq[cg]) * 0.125f;   // 1/sqrt(64)
    else if (cg < 2 * EDIM)
        kout[row * EDIM + (cg - EDIM)] = v2;
    else
        vout[row * EDIM + (cg - 2 * EDIM)] = v2 + bv[cg - 2 * EDIM];
}

// ---------------------------------------------------------------------------
// Kernel 3: fused attention. One block per (b,h); 7 K-tiles of 64 keys,
// K DMA'd to LDS double-buffer (vmcnt-counted, raw s_barrier), V straight
// to registers, per-wave online softmax, merge + new-k/v fold in epilogue.
// ---------------------------------------------------------------------------
__global__ __launch_bounds__(256, 4) void attn_fused(
    const float* __restrict__ q,       // [64][1280], pre-scaled
    const float* __restrict__ Kpast,   // [1280][448][64]
    const float* __restrict__ Vpast,
    const float* __restrict__ mask,    // [448]
    const float* __restrict__ knew,    // [64][1280]
    const float* __restrict__ vnew,
    float* __restrict__ merged)        // [64][1280]
{
    __shared__ __align__(16) float kbuf[2][64 * 64];   // 32 KB K double-buffer
    __shared__ __align__(16) float smask[PDIM];
    __shared__ float4 ctxw[4][16];
    __shared__ float mw[4], sw[4];

    const int bh = blockIdx.x;
    const int b  = bh / HDIM;
    const int hh = bh % HDIM;
    const int t  = threadIdx.x;
    const int w  = t >> 6;
    const int lane = t & 63;
    const int grp = t >> 4;     // 0..15: key group (rows grp, grp+16, +32, +48)
    const int dg  = t & 15;     // 16B slice within a 64-float row

    const float* Kb = Kpast + (size_t)bh * PDIM * DDIM;
    const float* Vb = Vpast + (size_t)bh * PDIM * DDIM;
    const int qbase = b * EDIM + hh * DDIM;

    // stage mask to LDS (448 floats, float2 per thread)
    if (t < 224) {
        float2 mv = *reinterpret_cast<const float2*>(mask + t * 2);
        *reinterpret_cast<float2*>(&smask[t * 2]) = mv;
    }
    const float4 qv = *reinterpret_cast<const float4*>(q + qbase + dg * 4);

    // prologue: DMA tiles 0 and 1 (8 outstanding per wave)
    dma_tile(Kb, kbuf[0], w, lane);
    dma_tile(Kb + 4096, kbuf[1], w, lane);

    float4 acc = make_float4(0.f, 0.f, 0.f, 0.f);
    float Sp = 0.f;
    float M  = -3.4e38f;

#pragma unroll
    for (int c = 0; c < NTILE; ++c) {
        // wait own tile-c DMA (allow tile c+1/c+2 in flight), then barrier
        if (c < NTILE - 1) {
            asm volatile("s_waitcnt vmcnt(4) lgkmcnt(0)" ::: "memory");
        } else {
            asm volatile("s_waitcnt vmcnt(0) lgkmcnt(0)" ::: "memory");
        }
        __builtin_amdgcn_s_barrier();
        __builtin_amdgcn_sched_barrier(0);

        // V for this tile: straight to registers, coalesced 1KB/wave-instr
        const float* Vt = Vb + (size_t)(c * 64 + grp) * DDIM + dg * 4;
        float4 v0 = *reinterpret_cast<const float4*>(Vt);
        float4 v1 = *reinterpret_cast<const float4*>(Vt + 16 * DDIM);
        float4 v2 = *reinterpret_cast<const float4*>(Vt + 32 * DDIM);
        float4 v3 = *reinterpret_cast<const float4*>(Vt + 48 * DDIM);

        // scores from K in LDS
        const float* kb = kbuf[c & 1];
        float4 k0 = *reinterpret_cast<const float4*>(kb + grp * DDIM + dg * 4);
        float4 k1 = *reinterpret_cast<const float4*>(kb + (grp + 16) * DDIM + dg * 4);
        float4 k2 = *reinterpret_cast<const float4*>(kb + (grp + 32) * DDIM + dg * 4);
        float4 k3 = *reinterpret_cast<const float4*>(kb + (grp + 48) * DDIM + dg * 4);
        float s0 = dot4(qv, k0), s1 = dot4(qv, k1);
        float s2 = dot4(qv, k2), s3 = dot4(qv, k3);
#pragma unroll
        for (int off = 8; off; off >>= 1) {
            s0 += __shfl_xor(s0, off, 16);
            s1 += __shfl_xor(s1, off, 16);
            s2 += __shfl_xor(s2, off, 16);
            s3 += __shfl_xor(s3, off, 16);
        }
        s0 += smask[c * 64 + grp];
        s1 += smask[c * 64 + grp + 16];
        s2 += smask[c * 64 + grp + 32];
        s3 += smask[c * 64 + grp + 48];

        // wave max over its 16 keys
        float m4 = fmaxf(fmaxf(s0, s1), fmaxf(s2, s3));
        m4 = fmaxf(m4, __shfl_xor(m4, 16, 64));
        m4 = fmaxf(m4, __shfl_xor(m4, 32, 64));
        const float newM = fmaxf(M, m4);
        const float sc = __expf(M - newM);   // first tile: exp(-huge) = 0
        M = newM;

        const float p0 = __expf(s0 - M), p1 = __expf(s1 - M);
        const float p2 = __expf(s2 - M), p3 = __expf(s3 - M);
        Sp = Sp * sc + (p0 + p1 + p2 + p3);
        acc.x = acc.x * sc + p0 * v0.x + p1 * v1.x + p2 * v2.x + p3 * v3.x;
        acc.y = acc.y * sc + p0 * v0.y + p1 * v1.y + p2 * v2.y + p3 * v3.y;
        acc.z = acc.z * sc + p0 * v0.z + p1 * v1.z + p2 * v2.z + p3 * v3.z;
        acc.w = acc.w * sc + p0 * v0.w + p1 * v1.w + p2 * v2.w + p3 * v3.w;

        // all waves done reading kbuf[c&1]; then overwrite it with tile c+2
        asm volatile("s_waitcnt lgkmcnt(0)" ::: "memory");
        __builtin_amdgcn_s_barrier();
        __builtin_amdgcn_sched_barrier(0);
        if (c + 2 < NTILE)
            dma_tile(Kb + (size_t)(c + 2) * 4096, kbuf[c & 1], w, lane);
    }

    // wave-level reduce over the 4 key-groups
    acc.x += __shfl_xor(acc.x, 16, 64); acc.y += __shfl_xor(acc.y, 16, 64);
    acc.z += __shfl_xor(acc.z, 16, 64); acc.w += __shfl_xor(acc.w, 16, 64);
    acc.x += __shfl_xor(acc.x, 32, 64); acc.y += __shfl_xor(acc.y, 32, 64);
    acc.z += __shfl_xor(acc.z, 32, 64); acc.w += __shfl_xor(acc.w, 32, 64);
    Sp += __shfl_xor(Sp, 16, 64);
    Sp += __shfl_xor(Sp, 32, 64);
    if (lane < 16) ctxw[w][lane] = acc;
    if (lane == 0) { mw[w] = M; sw[w] = Sp; }
    __syncthreads();

    if (t < 16) {
        float4 knv = *reinterpret_cast<const float4*>(knew + qbase + t * 4);
        float4 vnv = *reinterpret_cast<const float4*>(vnew + qbase + t * 4);
        float4 qv2 = *reinterpret_cast<const float4*>(q + qbase + t * 4);
        float sn = dot4(qv2, knv);
#pragma unroll
        for (int off = 8; off; off >>= 1) sn += __shfl_xor(sn, off, 16);

        const float Mf = fmaxf(fmaxf(fmaxf(mw[0], mw[1]), fmaxf(mw[2], mw[3])), sn);
        const float e0 = __expf(mw[0] - Mf), e1 = __expf(mw[1] - Mf);
        const float e2 = __expf(mw[2] - Mf), e3 = __expf(mw[3] - Mf);
        const float en = __expf(sn - Mf);
        const float S = sw[0] * e0 + sw[1] * e1 + sw[2] * e2 + sw[3] * e3 + en;
        const float4 c0 = ctxw[0][t], c1 = ctxw[1][t], c2 = ctxw[2][t], c3 = ctxw[3][t];
        float4 r;
        r.x = (c0.x * e0 + c1.x * e1 + c2.x * e2 + c3.x * e3 + en * vnv.x) / S;
        r.y = (c0.y * e0 + c1.y * e1 + c2.y * e2 + c3.y * e3 + en * vnv.y) / S;
        r.z = (c0.z * e0 + c1.z * e1 + c2.z * e2 + c3.z * e3 + en * vnv.z) / S;
        r.w = (c0.w * e0 + c1.w * e1 + c2.w * e2 + c3.w * e3 + en * vnv.w) / S;
        *reinterpret_cast<float4*>(merged + qbase + t * 4) = r;
    }
}

// ---------------------------------------------------------------------------
// Kernel 4: output projection, LDS-staged weights.
// ---------------------------------------------------------------------------
__global__ __launch_bounds__(256) void proj_out(
    const float* __restrict__ x,
    const float* __restrict__ Wo,
    float* __restrict__ partial)
{
    __shared__ float Wt[CTILE * ECHUNK];

    const int wave = threadIdx.x >> 6;
    const int lane = threadIdx.x & 63;
    const int colbase = blockIdx.x * CTILE;
    const int e0 = blockIdx.y * ECHUNK;

#pragma unroll
    for (int i = 0; i < 10; ++i) {
        int i4 = (i * 256 + threadIdx.x) * 4;
        int c  = i4 / ECHUNK;
        int e  = i4 - c * ECHUNK;
        *reinterpret_cast<float4*>(&Wt[i4]) =
            *reinterpret_cast<const float4*>(&Wo[(size_t)(colbase + c) * EDIM + e0 + e]);
    }
    __syncthreads();

    float acc[8];
#pragma unroll
    for (int c = 0; c < 8; ++c) acc[c] = 0.f;

    const float4* xp = reinterpret_cast<const float4*>(x + lane * EDIM + e0);
    const int c0 = wave * 8;
#pragma unroll 4
    for (int eg = 0; eg < ECHUNK / 4; ++eg) {
        float4 hv = xp[eg];
#pragma unroll
        for (int c = 0; c < 8; ++c) {
            float4 wv = *reinterpret_cast<const float4*>(&Wt[(c0 + c) * ECHUNK + eg * 4]);
            acc[c] += dot4(hv, wv);
        }
    }
#pragma unroll
    for (int c = 0; c < 8; ++c)
        partial[((size_t)blockIdx.y * EDIM + colbase + c0 + c) * 64 + lane] = acc[c];
}

// ---------------------------------------------------------------------------
// Kernel 5: reduce output-projection partials + bias -> d_out[0:81920]
// ---------------------------------------------------------------------------
__global__ __launch_bounds__(256) void reduce_out(
    const float* __restrict__ partial, const float* __restrict__ bo,
    float* __restrict__ out)
{
    __shared__ float tile[256];
    const int cg0 = blockIdx.x * 4;
    const int idx = cg0 * 64 + threadIdx.x;
    float v = partial[idx] + partial[81920 + idx]
            + partial[163840 + idx] + partial[245760 + idx];
    tile[threadIdx.x] = v;
    __syncthreads();
    const int row = threadIdx.x >> 2;
    const int c   = threadIdx.x & 3;
    const int cg  = cg0 + c;
    out[row * EDIM + cg] = tile[c * 64 + row] + bo[cg];
}

// ---------------------------------------------------------------------------
extern "C" void kernel_launch(void* const* d_in, const int* in_sizes, int n_in,
                              void* d_out, int out_size, void* d_ws, size_t ws_size,
                              hipStream_t stream)
{
    const float* h    = (const float*)d_in[0];
    const float* pk   = (const float*)d_in[1];
    const float* pv   = (const float*)d_in[2];
    const float* mask = (const float*)d_in[3];
    const float* Wq   = (const float*)d_in[4];
    const float* bq   = (const float*)d_in[5];
    const float* Wk   = (const float*)d_in[6];
    const float* Wv   = (const float*)d_in[7];
    const float* bv   = (const float*)d_in[8];
    const float* Wo   = (const float*)d_in[9];
    const float* bo   = (const float*)d_in[10];

    float* out  = (float*)d_out;            // [64][1280]
    float* kout = (float*)d_out + 81920;    // new_k
    float* vout = (float*)d_out + 163840;   // new_v

    float* ws    = (float*)d_ws;
    float* partP = ws;                        // 983040 floats (dead after reduce_proj)
    float* qbuf  = ws + 983040;               // 81920
    float* mrg   = ws + 983040 + 81920;       // 81920
    float* partO = ws + 983040 + 163840;      // 327680

    proj_qkv<<<dim3(NCOL / CTILE, NCHUNK), 256, 0, stream>>>(h, Wq, Wk, Wv, partP);
    reduce_proj<<<dim3(NCOL / 4), 256, 0, stream>>>(partP, bq, bv, qbuf, kout, vout);
    attn_fused<<<dim3(BDIM * HDIM), 256, 0, stream>>>(qbuf, pk, pv, mask, kout, vout, mrg);
    proj_out<<<dim3(EDIM / CTILE, NCHUNK), 256, 0, stream>>>(mrg, Wo, partO);
    reduce_out<<<dim3(EDIM / 4), 256, 0, stream>>>(partO, bo, out);
}

// Round 5
// 102.177 us; speedup vs baseline: 1.2743x; 1.2743x over previous
//
#include <hip/hip_runtime.h>

#define EDIM 1280
#define BDIM 64
#define HDIM 20
#define PDIM 448
#define DDIM 64
#define NCOL 3840      // 3*EDIM (q,k,v columns fused)
#define NCHUNK 4
#define ECHUNK 320     // EDIM / NCHUNK
#define CTILE 32       // columns per block
#define KCHUNKS 7      // 448 / 64 key chunks for split attention

__device__ __forceinline__ float dot4(float4 a, float4 b) {
    return a.x * b.x + a.y * b.y + a.z * b.z + a.w * b.w;
}

// ---------------------------------------------------------------------------
// Kernel 1: fused QKV projection, LDS-staged weights.
// ---------------------------------------------------------------------------
__global__ __launch_bounds__(256) void proj_qkv(
    const float* __restrict__ h,
    const float* __restrict__ Wq, const float* __restrict__ Wk,
    const float* __restrict__ Wv,
    float* __restrict__ partial)
{
    __shared__ float Wt[CTILE * ECHUNK];   // 40 KB

    const int wave = threadIdx.x >> 6;
    const int lane = threadIdx.x & 63;
    const int colbase = blockIdx.x * CTILE;
    const int e0 = blockIdx.y * ECHUNK;

    const float* W; int wc;
    if (colbase < EDIM)          { W = Wq; wc = colbase; }
    else if (colbase < 2 * EDIM) { W = Wk; wc = colbase - EDIM; }
    else                         { W = Wv; wc = colbase - 2 * EDIM; }

#pragma unroll
    for (int i = 0; i < 10; ++i) {
        int i4 = (i * 256 + threadIdx.x) * 4;
        int c  = i4 / ECHUNK;
        int e  = i4 - c * ECHUNK;
        *reinterpret_cast<float4*>(&Wt[i4]) =
            *reinterpret_cast<const float4*>(&W[(size_t)(wc + c) * EDIM + e0 + e]);
    }
    __syncthreads();

    float acc[8];
#pragma unroll
    for (int c = 0; c < 8; ++c) acc[c] = 0.f;

    const float4* hp = reinterpret_cast<const float4*>(h + lane * EDIM + e0);
    const int c0 = wave * 8;
#pragma unroll 4
    for (int eg = 0; eg < ECHUNK / 4; ++eg) {
        float4 hv = hp[eg];
#pragma unroll
        for (int c = 0; c < 8; ++c) {
            float4 wv = *reinterpret_cast<const float4*>(&Wt[(c0 + c) * ECHUNK + eg * 4]);
            acc[c] += dot4(hv, wv);
        }
    }
#pragma unroll
    for (int c = 0; c < 8; ++c)
        partial[((size_t)blockIdx.y * NCOL + colbase + c0 + c) * 64 + lane] = acc[c];
}

// ---------------------------------------------------------------------------
// Kernel 2: reduce QKV partials.
// ---------------------------------------------------------------------------
__global__ __launch_bounds__(256) void reduce_proj(
    const float* __restrict__ partial,
    const float* __restrict__ bq, const float* __restrict__ bv,
    float* __restrict__ qout, float* __restrict__ kout, float* __restrict__ vout)
{
    __shared__ float tile[256];
    const int cg0 = blockIdx.x * 4;
    const int idx = cg0 * 64 + threadIdx.x;
    float v = partial[idx] + partial[245760 + idx]
            + partial[491520 + idx] + partial[737280 + idx];
    tile[threadIdx.x] = v;
    __syncthreads();
    const int row = threadIdx.x >> 2;
    const int c   = threadIdx.x & 3;
    const int cg  = cg0 + c;
    const float v2 = tile[c * 64 + row];
    if (cg < EDIM)
        qout[row * EDIM + cg] = (v2 + bq[cg]) * 0.125f;   // 1/sqrt(64)
    else if (cg < 2 * EDIM)
        kout[row * EDIM + (cg - EDIM)] = v2;
    else
        vout[row * EDIM + (cg - 2 * EDIM)] = v2 + bv[cg - 2 * EDIM];
}

// ---------------------------------------------------------------------------
// Kernel 3a: split-K attention partial. Block = (chunk, bh), 64 keys/chunk.
// All 8 KV loads + q pinned BEFORE any consumer via sched_barrier(0):
// guaranteed 8 x 1KB in flight per wave (the compiler may NOT sink them).
// ---------------------------------------------------------------------------
__global__ __launch_bounds__(256) void attn_part(
    const float* __restrict__ q,       // [64][1280], pre-scaled
    const float* __restrict__ Kpast,   // [1280][448][64]
    const float* __restrict__ Vpast,
    const float* __restrict__ mask,    // [448]
    float* __restrict__ ctxbuf,        // [1280][7][64]
    float* __restrict__ msbuf)         // [1280][7][2]  (max, sum)
{
    __shared__ float redm[4];
    __shared__ float reds[4];
    __shared__ float4 ctxp[4][16];

    const int chunk = blockIdx.x;          // 0..6
    const int bh    = blockIdx.y;          // 0..1279
    const int b  = bh / HDIM;
    const int hh = bh % HDIM;
    const int t  = threadIdx.x;
    const int w  = t >> 6;
    const int lane = t & 63;
    const int grp = t >> 4;                // 0..15
    const int dg  = t & 15;                // float4 slice of the 64-float row

    const int j0 = chunk * 64 + grp;       // keys j0, j0+16, j0+32, j0+48
    const size_t rowbase = ((size_t)bh * PDIM + j0) * DDIM + dg * 4;
    const float* Kr = Kpast + rowbase;
    const float* Vr = Vpast + rowbase;

    // ---- issue ALL loads up front; sched_barrier(0) pins them here ----
    float4 k0 = *reinterpret_cast<const float4*>(Kr);
    float4 k1 = *reinterpret_cast<const float4*>(Kr + 16 * DDIM);
    float4 k2 = *reinterpret_cast<const float4*>(Kr + 32 * DDIM);
    float4 k3 = *reinterpret_cast<const float4*>(Kr + 48 * DDIM);
    float4 v0 = *reinterpret_cast<const float4*>(Vr);
    float4 v1 = *reinterpret_cast<const float4*>(Vr + 16 * DDIM);
    float4 v2 = *reinterpret_cast<const float4*>(Vr + 32 * DDIM);
    float4 v3 = *reinterpret_cast<const float4*>(Vr + 48 * DDIM);
    const float4 qv = *reinterpret_cast<const float4*>(q + b * EDIM + hh * DDIM + dg * 4);
    __builtin_amdgcn_sched_barrier(0);

    // ---- scores ----
    float s0 = dot4(qv, k0), s1 = dot4(qv, k1), s2 = dot4(qv, k2), s3 = dot4(qv, k3);
#pragma unroll
    for (int off = 8; off; off >>= 1) {
        s0 += __shfl_xor(s0, off, 16);
        s1 += __shfl_xor(s1, off, 16);
        s2 += __shfl_xor(s2, off, 16);
        s3 += __shfl_xor(s3, off, 16);
    }
    s0 += mask[j0]; s1 += mask[j0 + 16]; s2 += mask[j0 + 32]; s3 += mask[j0 + 48];

    // ---- block max ----
    float m4 = fmaxf(fmaxf(s0, s1), fmaxf(s2, s3));
    m4 = fmaxf(m4, __shfl_xor(m4, 16, 64));
    m4 = fmaxf(m4, __shfl_xor(m4, 32, 64));
    if (lane == 0) redm[w] = m4;
    __syncthreads();
    const float mx = fmaxf(fmaxf(redm[0], redm[1]), fmaxf(redm[2], redm[3]));

    // ---- exp, local sum, weighted-V ----
    float p0 = __expf(s0 - mx), p1 = __expf(s1 - mx);
    float p2 = __expf(s2 - mx), p3 = __expf(s3 - mx);
    float ls = p0 + p1 + p2 + p3;
    ls += __shfl_xor(ls, 16, 64);
    ls += __shfl_xor(ls, 32, 64);

    float4 acc;
    acc.x = p0 * v0.x + p1 * v1.x + p2 * v2.x + p3 * v3.x;
    acc.y = p0 * v0.y + p1 * v1.y + p2 * v2.y + p3 * v3.y;
    acc.z = p0 * v0.z + p1 * v1.z + p2 * v2.z + p3 * v3.z;
    acc.w = p0 * v0.w + p1 * v1.w + p2 * v2.w + p3 * v3.w;
    acc.x += __shfl_xor(acc.x, 16, 64); acc.y += __shfl_xor(acc.y, 16, 64);
    acc.z += __shfl_xor(acc.z, 16, 64); acc.w += __shfl_xor(acc.w, 16, 64);
    acc.x += __shfl_xor(acc.x, 32, 64); acc.y += __shfl_xor(acc.y, 32, 64);
    acc.z += __shfl_xor(acc.z, 32, 64); acc.w += __shfl_xor(acc.w, 32, 64);

    if (lane == 0) reds[w] = ls;
    if (lane < 16) ctxp[w][lane] = acc;
    __syncthreads();

    if (t < 16) {
        float4 a0 = ctxp[0][t], a1 = ctxp[1][t], a2 = ctxp[2][t], a3 = ctxp[3][t];
        float4 r;
        r.x = a0.x + a1.x + a2.x + a3.x;
        r.y = a0.y + a1.y + a2.y + a3.y;
        r.z = a0.z + a1.z + a2.z + a3.z;
        r.w = a0.w + a1.w + a2.w + a3.w;
        *reinterpret_cast<float4*>(ctxbuf + ((size_t)bh * KCHUNKS + chunk) * 64 + t * 4) = r;
    }
    if (t == 0) {
        msbuf[((size_t)bh * KCHUNKS + chunk) * 2 + 0] = mx;
        msbuf[((size_t)bh * KCHUNKS + chunk) * 2 + 1] = reds[0] + reds[1] + reds[2] + reds[3];
    }
}

// ---------------------------------------------------------------------------
// Kernel 3b: combine 7 chunk records + new key/value, online softmax merge.
// ---------------------------------------------------------------------------
__global__ __launch_bounds__(256) void attn_combine(
    const float* __restrict__ q,       // pre-scaled
    const float* __restrict__ knew,    // [64][1280]
    const float* __restrict__ vnew,
    const float* __restrict__ ctxbuf,
    const float* __restrict__ msbuf,
    float* __restrict__ merged)        // [64][1280]
{
    const int unit = blockIdx.x * 4 + (threadIdx.x >> 6);   // bh
    const int lane = threadIdx.x & 63;
    const int b  = unit / HDIM;
    const int hh = unit % HDIM;

    float mc[KCHUNKS], sc[KCHUNKS];
    float M = -3.4e38f;
#pragma unroll
    for (int c = 0; c < KCHUNKS; ++c) {
        mc[c] = msbuf[((size_t)unit * KCHUNKS + c) * 2 + 0];
        sc[c] = msbuf[((size_t)unit * KCHUNKS + c) * 2 + 1];
        M = fmaxf(M, mc[c]);
    }

    // new key score
    const int base = b * EDIM + hh * DDIM + lane;
    float sn = q[base] * knew[base];
#pragma unroll
    for (int off = 32; off; off >>= 1) sn += __shfl_xor(sn, off, 64);

    const float M2 = fmaxf(M, sn);
    const float pn = __expf(sn - M2);
    float S   = pn;
    float ctx = pn * vnew[base];
#pragma unroll
    for (int c = 0; c < KCHUNKS; ++c) {
        float e = __expf(mc[c] - M2);
        S   += sc[c] * e;
        ctx += e * ctxbuf[((size_t)unit * KCHUNKS + c) * 64 + lane];
    }
    merged[base] = ctx / S;
}

// ---------------------------------------------------------------------------
// Kernel 4: output projection, LDS-staged weights.
// ---------------------------------------------------------------------------
__global__ __launch_bounds__(256) void proj_out(
    const float* __restrict__ x,
    const float* __restrict__ Wo,
    float* __restrict__ partial)
{
    __shared__ float Wt[CTILE * ECHUNK];

    const int wave = threadIdx.x >> 6;
    const int lane = threadIdx.x & 63;
    const int colbase = blockIdx.x * CTILE;
    const int e0 = blockIdx.y * ECHUNK;

#pragma unroll
    for (int i = 0; i < 10; ++i) {
        int i4 = (i * 256 + threadIdx.x) * 4;
        int c  = i4 / ECHUNK;
        int e  = i4 - c * ECHUNK;
        *reinterpret_cast<float4*>(&Wt[i4]) =
            *reinterpret_cast<const float4*>(&Wo[(size_t)(colbase + c) * EDIM + e0 + e]);
    }
    __syncthreads();

    float acc[8];
#pragma unroll
    for (int c = 0; c < 8; ++c) acc[c] = 0.f;

    const float4* xp = reinterpret_cast<const float4*>(x + lane * EDIM + e0);
    const int c0 = wave * 8;
#pragma unroll 4
    for (int eg = 0; eg < ECHUNK / 4; ++eg) {
        float4 hv = xp[eg];
#pragma unroll
        for (int c = 0; c < 8; ++c) {
            float4 wv = *reinterpret_cast<const float4*>(&Wt[(c0 + c) * ECHUNK + eg * 4]);
            acc[c] += dot4(hv, wv);
        }
    }
#pragma unroll
    for (int c = 0; c < 8; ++c)
        partial[((size_t)blockIdx.y * EDIM + colbase + c0 + c) * 64 + lane] = acc[c];
}

// ---------------------------------------------------------------------------
// Kernel 5: reduce output-projection partials + bias -> d_out[0:81920]
// ---------------------------------------------------------------------------
__global__ __launch_bounds__(256) void reduce_out(
    const float* __restrict__ partial, const float* __restrict__ bo,
    float* __restrict__ out)
{
    __shared__ float tile[256];
    const int cg0 = blockIdx.x * 4;
    const int idx = cg0 * 64 + threadIdx.x;
    float v = partial[idx] + partial[81920 + idx]
            + partial[163840 + idx] + partial[245760 + idx];
    tile[threadIdx.x] = v;
    __syncthreads();
    const int row = threadIdx.x >> 2;
    const int c   = threadIdx.x & 3;
    const int cg  = cg0 + c;
    out[row * EDIM + cg] = tile[c * 64 + row] + bo[cg];
}

// ---------------------------------------------------------------------------
extern "C" void kernel_launch(void* const* d_in, const int* in_sizes, int n_in,
                              void* d_out, int out_size, void* d_ws, size_t ws_size,
                              hipStream_t stream)
{
    const float* h    = (const float*)d_in[0];
    const float* pk   = (const float*)d_in[1];
    const float* pv   = (const float*)d_in[2];
    const float* mask = (const float*)d_in[3];
    const float* Wq   = (const float*)d_in[4];
    const float* bq   = (const float*)d_in[5];
    const float* Wk   = (const float*)d_in[6];
    const float* Wv   = (const float*)d_in[7];
    const float* bv   = (const float*)d_in[8];
    const float* Wo   = (const float*)d_in[9];
    const float* bo   = (const float*)d_in[10];

    float* out  = (float*)d_out;            // [64][1280]
    float* kout = (float*)d_out + 81920;    // new_k
    float* vout = (float*)d_out + 163840;   // new_v

    float* ws    = (float*)d_ws;
    float* partP = ws;                        // 983040 floats (dead after reduce_proj)
    float* ctxb  = ws;                        // aliases partP: 1280*7*64 = 573440
    float* msb   = ws + 573440;               // 1280*7*2 = 17920 (still < 983040)
    float* qbuf  = ws + 983040;               // 81920
    float* mrg   = ws + 983040 + 81920;       // 81920
    float* partO = ws + 983040 + 163840;      // 327680

    proj_qkv<<<dim3(NCOL / CTILE, NCHUNK), 256, 0, stream>>>(h, Wq, Wk, Wv, partP);
    reduce_proj<<<dim3(NCOL / 4), 256, 0, stream>>>(partP, bq, bv, qbuf, kout, vout);
    attn_part<<<dim3(KCHUNKS, BDIM * HDIM), 256, 0, stream>>>(qbuf, pk, pv, mask, ctxb, msb);
    attn_combine<<<dim3(BDIM * HDIM / 4), 256, 0, stream>>>(qbuf, kout, vout, ctxb, msb, mrg);
    proj_out<<<dim3(EDIM / CTILE, NCHUNK), 256, 0, stream>>>(mrg, Wo, partO);
    reduce_out<<<dim3(EDIM / 4), 256, 0, stream>>>(partO, bo, out);
}

// Round 6
// 100.794 us; speedup vs baseline: 1.2918x; 1.0137x over previous
//
#include <hip/hip_runtime.h>

#define EDIM 1280
#define BDIM 64
#define HDIM 20
#define PDIM 448
#define DDIM 64
#define NCOL 3840      // 3*EDIM (q,k,v columns fused)
#define NCHUNK 4
#define ECHUNK 320     // EDIM / NCHUNK
#define CTILE 32       // columns per block
#define KCHUNKS 7      // 448 / 64 key chunks for split attention

__device__ __forceinline__ float dot4(float4 a, float4 b) {
    return a.x * b.x + a.y * b.y + a.z * b.z + a.w * b.w;
}

// async global->LDS DMA: 16B per lane, LDS dest = wave-uniform base + lane*16
__device__ __forceinline__ void dma16(const float* g, float* l) {
    __builtin_amdgcn_global_load_lds(
        (const __attribute__((address_space(1))) void*)(g),
        (__attribute__((address_space(3))) void*)(l),
        16, 0, 0);
}

// stage one 64x64-float tile (16 KB): 4 DMA instrs per wave (verified in R4)
__device__ __forceinline__ void dma_tile(const float* tbase, float* lbase,
                                         int w, int lane) {
#pragma unroll
    for (int r = 0; r < 4; ++r) {
        dma16(tbase + (size_t)(r * 256 + w * 64 + lane) * 4,
              lbase + (r * 256 + w * 64) * 4);
    }
}

// ---------------------------------------------------------------------------
// Kernel 1: fused QKV projection, LDS-staged weights.
// ---------------------------------------------------------------------------
__global__ __launch_bounds__(256) void proj_qkv(
    const float* __restrict__ h,
    const float* __restrict__ Wq, const float* __restrict__ Wk,
    const float* __restrict__ Wv,
    float* __restrict__ partial)
{
    __shared__ float Wt[CTILE * ECHUNK];   // 40 KB

    const int wave = threadIdx.x >> 6;
    const int lane = threadIdx.x & 63;
    const int colbase = blockIdx.x * CTILE;
    const int e0 = blockIdx.y * ECHUNK;

    const float* W; int wc;
    if (colbase < EDIM)          { W = Wq; wc = colbase; }
    else if (colbase < 2 * EDIM) { W = Wk; wc = colbase - EDIM; }
    else                         { W = Wv; wc = colbase - 2 * EDIM; }

#pragma unroll
    for (int i = 0; i < 10; ++i) {
        int i4 = (i * 256 + threadIdx.x) * 4;
        int c  = i4 / ECHUNK;
        int e  = i4 - c * ECHUNK;
        *reinterpret_cast<float4*>(&Wt[i4]) =
            *reinterpret_cast<const float4*>(&W[(size_t)(wc + c) * EDIM + e0 + e]);
    }
    __syncthreads();

    float acc[8];
#pragma unroll
    for (int c = 0; c < 8; ++c) acc[c] = 0.f;

    const float4* hp = reinterpret_cast<const float4*>(h + lane * EDIM + e0);
    const int c0 = wave * 8;
#pragma unroll 4
    for (int eg = 0; eg < ECHUNK / 4; ++eg) {
        float4 hv = hp[eg];
#pragma unroll
        for (int c = 0; c < 8; ++c) {
            float4 wv = *reinterpret_cast<const float4*>(&Wt[(c0 + c) * ECHUNK + eg * 4]);
            acc[c] += dot4(hv, wv);
        }
    }
#pragma unroll
    for (int c = 0; c < 8; ++c)
        partial[((size_t)blockIdx.y * NCOL + colbase + c0 + c) * 64 + lane] = acc[c];
}

// ---------------------------------------------------------------------------
// Kernel 2: reduce QKV partials.
// ---------------------------------------------------------------------------
__global__ __launch_bounds__(256) void reduce_proj(
    const float* __restrict__ partial,
    const float* __restrict__ bq, const float* __restrict__ bv,
    float* __restrict__ qout, float* __restrict__ kout, float* __restrict__ vout)
{
    __shared__ float tile[256];
    const int cg0 = blockIdx.x * 4;
    const int idx = cg0 * 64 + threadIdx.x;
    float v = partial[idx] + partial[245760 + idx]
            + partial[491520 + idx] + partial[737280 + idx];
    tile[threadIdx.x] = v;
    __syncthreads();
    const int row = threadIdx.x >> 2;
    const int c   = threadIdx.x & 3;
    const int cg  = cg0 + c;
    const float v2 = tile[c * 64 + row];
    if (cg < EDIM)
        qout[row * EDIM + cg] = (v2 + bq[cg]) * 0.125f;   // 1/sqrt(64)
    else if (cg < 2 * EDIM)
        kout[row * EDIM + (cg - EDIM)] = v2;
    else
        vout[row * EDIM + (cg - 2 * EDIM)] = v2 + bv[cg - 2 * EDIM];
}

// ---------------------------------------------------------------------------
// Kernel 3a: split-K attention partial, DMA-staged K AND V.
// Block = (chunk, bh), 64 keys. Both 16KB tiles DMA'd to LDS with zero VGPR
// cost (compiler cannot sink them) -> guaranteed 32KB in flight per block.
// One full-drain barrier, then all compute from LDS. Reductions reuse kbuf
// (after a barrier) so LDS stays at exactly 32768B -> 5 blocks/CU.
// ---------------------------------------------------------------------------
__global__ __launch_bounds__(256) void attn_part(
    const float* __restrict__ q,       // [64][1280], pre-scaled
    const float* __restrict__ Kpast,   // [1280][448][64]
    const float* __restrict__ Vpast,
    const float* __restrict__ mask,    // [448]
    float* __restrict__ ctxbuf,        // [1280][7][64]
    float* __restrict__ msbuf)         // [1280][7][2]  (max, sum)
{
    __shared__ __align__(16) float kbuf[4096];   // 16 KB (reused for reductions)
    __shared__ __align__(16) float vbuf[4096];   // 16 KB

    const int chunk = blockIdx.x;          // 0..6
    const int bh    = blockIdx.y;          // 0..1279
    const int b  = bh / HDIM;
    const int hh = bh % HDIM;
    const int t  = threadIdx.x;
    const int w  = t >> 6;
    const int lane = t & 63;
    const int grp = t >> 4;                // 0..15
    const int dg  = t & 15;                // float4 slice of the 64-float row

    const float* Kt = Kpast + ((size_t)bh * PDIM + chunk * 64) * DDIM;
    const float* Vt = Vpast + ((size_t)bh * PDIM + chunk * 64) * DDIM;

    // ---- fire-and-forget DMA of both tiles (8 x 1KB per wave in flight) ----
    dma_tile(Kt, kbuf, w, lane);
    dma_tile(Vt, vbuf, w, lane);

    const int j0 = chunk * 64 + grp;       // keys j0, j0+16, j0+32, j0+48
    const float4 qv = *reinterpret_cast<const float4*>(q + b * EDIM + hh * DDIM + dg * 4);
    const float mk0 = mask[j0], mk1 = mask[j0 + 16];
    const float mk2 = mask[j0 + 32], mk3 = mask[j0 + 48];

    __syncthreads();   // vmcnt(0)+lgkmcnt(0) drain + barrier: tiles resident

    // ---- scores from LDS K ----
    float4 k0 = *reinterpret_cast<const float4*>(kbuf + grp * DDIM + dg * 4);
    float4 k1 = *reinterpret_cast<const float4*>(kbuf + (grp + 16) * DDIM + dg * 4);
    float4 k2 = *reinterpret_cast<const float4*>(kbuf + (grp + 32) * DDIM + dg * 4);
    float4 k3 = *reinterpret_cast<const float4*>(kbuf + (grp + 48) * DDIM + dg * 4);
    float s0 = dot4(qv, k0), s1 = dot4(qv, k1), s2 = dot4(qv, k2), s3 = dot4(qv, k3);
#pragma unroll
    for (int off = 8; off; off >>= 1) {
        s0 += __shfl_xor(s0, off, 16);
        s1 += __shfl_xor(s1, off, 16);
        s2 += __shfl_xor(s2, off, 16);
        s3 += __shfl_xor(s3, off, 16);
    }
    s0 += mk0; s1 += mk1; s2 += mk2; s3 += mk3;

    // ---- wave max ----
    float m4 = fmaxf(fmaxf(s0, s1), fmaxf(s2, s3));
    m4 = fmaxf(m4, __shfl_xor(m4, 16, 64));
    m4 = fmaxf(m4, __shfl_xor(m4, 32, 64));

    __syncthreads();   // all waves done reading kbuf -> reusable as scratch
    float* redm = kbuf;                    // [4]
    float* reds = kbuf + 8;                // [4]
    float4* ctxp = reinterpret_cast<float4*>(kbuf + 16);   // [4][16]

    if (lane == 0) redm[w] = m4;
    __syncthreads();
    const float mx = fmaxf(fmaxf(redm[0], redm[1]), fmaxf(redm[2], redm[3]));

    // ---- exp, local sum, weighted-V from LDS ----
    float p0 = __expf(s0 - mx), p1 = __expf(s1 - mx);
    float p2 = __expf(s2 - mx), p3 = __expf(s3 - mx);
    float ls = p0 + p1 + p2 + p3;
    ls += __shfl_xor(ls, 16, 64);
    ls += __shfl_xor(ls, 32, 64);

    float4 v0 = *reinterpret_cast<const float4*>(vbuf + grp * DDIM + dg * 4);
    float4 v1 = *reinterpret_cast<const float4*>(vbuf + (grp + 16) * DDIM + dg * 4);
    float4 v2 = *reinterpret_cast<const float4*>(vbuf + (grp + 32) * DDIM + dg * 4);
    float4 v3 = *reinterpret_cast<const float4*>(vbuf + (grp + 48) * DDIM + dg * 4);

    float4 acc;
    acc.x = p0 * v0.x + p1 * v1.x + p2 * v2.x + p3 * v3.x;
    acc.y = p0 * v0.y + p1 * v1.y + p2 * v2.y + p3 * v3.y;
    acc.z = p0 * v0.z + p1 * v1.z + p2 * v2.z + p3 * v3.z;
    acc.w = p0 * v0.w + p1 * v1.w + p2 * v2.w + p3 * v3.w;
    acc.x += __shfl_xor(acc.x, 16, 64); acc.y += __shfl_xor(acc.y, 16, 64);
    acc.z += __shfl_xor(acc.z, 16, 64); acc.w += __shfl_xor(acc.w, 16, 64);
    acc.x += __shfl_xor(acc.x, 32, 64); acc.y += __shfl_xor(acc.y, 32, 64);
    acc.z += __shfl_xor(acc.z, 32, 64); acc.w += __shfl_xor(acc.w, 32, 64);

    if (lane == 0) reds[w] = ls;
    if (lane < 16) ctxp[w * 16 + lane] = acc;
    __syncthreads();

    if (t < 16) {
        float4 a0 = ctxp[t], a1 = ctxp[16 + t], a2 = ctxp[32 + t], a3 = ctxp[48 + t];
        float4 r;
        r.x = a0.x + a1.x + a2.x + a3.x;
        r.y = a0.y + a1.y + a2.y + a3.y;
        r.z = a0.z + a1.z + a2.z + a3.z;
        r.w = a0.w + a1.w + a2.w + a3.w;
        *reinterpret_cast<float4*>(ctxbuf + ((size_t)bh * KCHUNKS + chunk) * 64 + t * 4) = r;
    }
    if (t == 0) {
        msbuf[((size_t)bh * KCHUNKS + chunk) * 2 + 0] = mx;
        msbuf[((size_t)bh * KCHUNKS + chunk) * 2 + 1] = reds[0] + reds[1] + reds[2] + reds[3];
    }
}

// ---------------------------------------------------------------------------
// Kernel 3b: combine 7 chunk records + new key/value, online softmax merge.
// ---------------------------------------------------------------------------
__global__ __launch_bounds__(256) void attn_combine(
    const float* __restrict__ q,       // pre-scaled
    const float* __restrict__ knew,    // [64][1280]
    const float* __restrict__ vnew,
    const float* __restrict__ ctxbuf,
    const float* __restrict__ msbuf,
    float* __restrict__ merged)        // [64][1280]
{
    const int unit = blockIdx.x * 4 + (threadIdx.x >> 6);   // bh
    const int lane = threadIdx.x & 63;
    const int b  = unit / HDIM;
    const int hh = unit % HDIM;

    float mc[KCHUNKS], sc[KCHUNKS];
    float M = -3.4e38f;
#pragma unroll
    for (int c = 0; c < KCHUNKS; ++c) {
        mc[c] = msbuf[((size_t)unit * KCHUNKS + c) * 2 + 0];
        sc[c] = msbuf[((size_t)unit * KCHUNKS + c) * 2 + 1];
        M = fmaxf(M, mc[c]);
    }

    // new key score
    const int base = b * EDIM + hh * DDIM + lane;
    float sn = q[base] * knew[base];
#pragma unroll
    for (int off = 32; off; off >>= 1) sn += __shfl_xor(sn, off, 64);

    const float M2 = fmaxf(M, sn);
    const float pn = __expf(sn - M2);
    float S   = pn;
    float ctx = pn * vnew[base];
#pragma unroll
    for (int c = 0; c < KCHUNKS; ++c) {
        float e = __expf(mc[c] - M2);
        S   += sc[c] * e;
        ctx += e * ctxbuf[((size_t)unit * KCHUNKS + c) * 64 + lane];
    }
    merged[base] = ctx / S;
}

// ---------------------------------------------------------------------------
// Kernel 4: output projection, LDS-staged weights.
// ---------------------------------------------------------------------------
__global__ __launch_bounds__(256) void proj_out(
    const float* __restrict__ x,
    const float* __restrict__ Wo,
    float* __restrict__ partial)
{
    __shared__ float Wt[CTILE * ECHUNK];

    const int wave = threadIdx.x >> 6;
    const int lane = threadIdx.x & 63;
    const int colbase = blockIdx.x * CTILE;
    const int e0 = blockIdx.y * ECHUNK;

#pragma unroll
    for (int i = 0; i < 10; ++i) {
        int i4 = (i * 256 + threadIdx.x) * 4;
        int c  = i4 / ECHUNK;
        int e  = i4 - c * ECHUNK;
        *reinterpret_cast<float4*>(&Wt[i4]) =
            *reinterpret_cast<const float4*>(&Wo[(size_t)(colbase + c) * EDIM + e0 + e]);
    }
    __syncthreads();

    float acc[8];
#pragma unroll
    for (int c = 0; c < 8; ++c) acc[c] = 0.f;

    const float4* xp = reinterpret_cast<const float4*>(x + lane * EDIM + e0);
    const int c0 = wave * 8;
#pragma unroll 4
    for (int eg = 0; eg < ECHUNK / 4; ++eg) {
        float4 hv = xp[eg];
#pragma unroll
        for (int c = 0; c < 8; ++c) {
            float4 wv = *reinterpret_cast<const float4*>(&Wt[(c0 + c) * ECHUNK + eg * 4]);
            acc[c] += dot4(hv, wv);
        }
    }
#pragma unroll
    for (int c = 0; c < 8; ++c)
        partial[((size_t)blockIdx.y * EDIM + colbase + c0 + c) * 64 + lane] = acc[c];
}

// ---------------------------------------------------------------------------
// Kernel 5: reduce output-projection partials + bias -> d_out[0:81920]
// ---------------------------------------------------------------------------
__global__ __launch_bounds__(256) void reduce_out(
    const float* __restrict__ partial, const float* __restrict__ bo,
    float* __restrict__ out)
{
    __shared__ float tile[256];
    const int cg0 = blockIdx.x * 4;
    const int idx = cg0 * 64 + threadIdx.x;
    float v = partial[idx] + partial[81920 + idx]
            + partial[163840 + idx] + partial[245760 + idx];
    tile[threadIdx.x] = v;
    __syncthreads();
    const int row = threadIdx.x >> 2;
    const int c   = threadIdx.x & 3;
    const int cg  = cg0 + c;
    out[row * EDIM + cg] = tile[c * 64 + row] + bo[cg];
}

// ---------------------------------------------------------------------------
extern "C" void kernel_launch(void* const* d_in, const int* in_sizes, int n_in,
                              void* d_out, int out_size, void* d_ws, size_t ws_size,
                              hipStream_t stream)
{
    const float* h    = (const float*)d_in[0];
    const float* pk   = (const float*)d_in[1];
    const float* pv   = (const float*)d_in[2];
    const float* mask = (const float*)d_in[3];
    const float* Wq   = (const float*)d_in[4];
    const float* bq   = (const float*)d_in[5];
    const float* Wk   = (const float*)d_in[6];
    const float* Wv   = (const float*)d_in[7];
    const float* bv   = (const float*)d_in[8];
    const float* Wo   = (const float*)d_in[9];
    const float* bo   = (const float*)d_in[10];

    float* out  = (float*)d_out;            // [64][1280]
    float* kout = (float*)d_out + 81920;    // new_k
    float* vout = (float*)d_out + 163840;   // new_v

    float* ws    = (float*)d_ws;
    float* partP = ws;                        // 983040 floats (dead after reduce_proj)
    float* ctxb  = ws;                        // aliases partP: 1280*7*64 = 573440
    float* msb   = ws + 573440;               // 1280*7*2 = 17920 (still < 983040)
    float* qbuf  = ws + 983040;               // 81920
    float* mrg   = ws + 983040 + 81920;       // 81920
    float* partO = ws + 983040 + 163840;      // 327680

    proj_qkv<<<dim3(NCOL / CTILE, NCHUNK), 256, 0, stream>>>(h, Wq, Wk, Wv, partP);
    reduce_proj<<<dim3(NCOL / 4), 256, 0, stream>>>(partP, bq, bv, qbuf, kout, vout);
    attn_part<<<dim3(KCHUNKS, BDIM * HDIM), 256, 0, stream>>>(qbuf, pk, pv, mask, ctxb, msb);
    attn_combine<<<dim3(BDIM * HDIM / 4), 256, 0, stream>>>(qbuf, kout, vout, ctxb, msb, mrg);
    proj_out<<<dim3(EDIM / CTILE, NCHUNK), 256, 0, stream>>>(mrg, Wo, partO);
    reduce_out<<<dim3(EDIM / 4), 256, 0, stream>>>(partO, bo, out);
}

// Round 7
// 98.005 us; speedup vs baseline: 1.3286x; 1.0285x over previous
//
#include <hip/hip_runtime.h>

#define EDIM 1280
#define BDIM 64
#define HDIM 20
#define PDIM 448
#define DDIM 64
#define NCOL 3840      // 3*EDIM (q,k,v columns fused)
#define NCHUNK 4
#define ECHUNK 320     // EDIM / NCHUNK
#define CTILE 32       // columns per block
#define KCHUNKS 7      // 448 / 64 key chunks for split attention

__device__ __forceinline__ float dot4(float4 a, float4 b) {
    return a.x * b.x + a.y * b.y + a.z * b.z + a.w * b.w;
}

// async global->LDS DMA: 16B per lane, LDS dest = wave-uniform base + lane*16
// AUX = CPol bits (gfx950): 0 = default, 2 = NT (non-temporal, no L3 allocate)
template <int AUX>
__device__ __forceinline__ void dma16(const float* g, float* l) {
    __builtin_amdgcn_global_load_lds(
        (const __attribute__((address_space(1))) void*)(g),
        (__attribute__((address_space(3))) void*)(l),
        16, 0, AUX);
}

// stage one 64x64-float tile (16 KB): 4 DMA instrs per wave
template <int AUX>
__device__ __forceinline__ void dma_tile(const float* tbase, float* lbase,
                                         int w, int lane) {
#pragma unroll
    for (int r = 0; r < 4; ++r) {
        dma16<AUX>(tbase + (size_t)(r * 256 + w * 64 + lane) * 4,
                   lbase + (r * 256 + w * 64) * 4);
    }
}

// ---------------------------------------------------------------------------
// Kernel 1: fused QKV projection, LDS-staged weights.
// ---------------------------------------------------------------------------
__global__ __launch_bounds__(256) void proj_qkv(
    const float* __restrict__ h,
    const float* __restrict__ Wq, const float* __restrict__ Wk,
    const float* __restrict__ Wv,
    float* __restrict__ partial)
{
    __shared__ float Wt[CTILE * ECHUNK];   // 40 KB

    const int wave = threadIdx.x >> 6;
    const int lane = threadIdx.x & 63;
    const int colbase = blockIdx.x * CTILE;
    const int e0 = blockIdx.y * ECHUNK;

    const float* W; int wc;
    if (colbase < EDIM)          { W = Wq; wc = colbase; }
    else if (colbase < 2 * EDIM) { W = Wk; wc = colbase - EDIM; }
    else                         { W = Wv; wc = colbase - 2 * EDIM; }

#pragma unroll
    for (int i = 0; i < 10; ++i) {
        int i4 = (i * 256 + threadIdx.x) * 4;
        int c  = i4 / ECHUNK;
        int e  = i4 - c * ECHUNK;
        *reinterpret_cast<float4*>(&Wt[i4]) =
            *reinterpret_cast<const float4*>(&W[(size_t)(wc + c) * EDIM + e0 + e]);
    }
    __syncthreads();

    float acc[8];
#pragma unroll
    for (int c = 0; c < 8; ++c) acc[c] = 0.f;

    const float4* hp = reinterpret_cast<const float4*>(h + lane * EDIM + e0);
    const int c0 = wave * 8;
#pragma unroll 4
    for (int eg = 0; eg < ECHUNK / 4; ++eg) {
        float4 hv = hp[eg];
#pragma unroll
        for (int c = 0; c < 8; ++c) {
            float4 wv = *reinterpret_cast<const float4*>(&Wt[(c0 + c) * ECHUNK + eg * 4]);
            acc[c] += dot4(hv, wv);
        }
    }
#pragma unroll
    for (int c = 0; c < 8; ++c)
        partial[((size_t)blockIdx.y * NCOL + colbase + c0 + c) * 64 + lane] = acc[c];
}

// ---------------------------------------------------------------------------
// Kernel 2: reduce QKV partials.
// ---------------------------------------------------------------------------
__global__ __launch_bounds__(256) void reduce_proj(
    const float* __restrict__ partial,
    const float* __restrict__ bq, const float* __restrict__ bv,
    float* __restrict__ qout, float* __restrict__ kout, float* __restrict__ vout)
{
    __shared__ float tile[256];
    const int cg0 = blockIdx.x * 4;
    const int idx = cg0 * 64 + threadIdx.x;
    float v = partial[idx] + partial[245760 + idx]
            + partial[491520 + idx] + partial[737280 + idx];
    tile[threadIdx.x] = v;
    __syncthreads();
    const int row = threadIdx.x >> 2;
    const int c   = threadIdx.x & 3;
    const int cg  = cg0 + c;
    const float v2 = tile[c * 64 + row];
    if (cg < EDIM)
        qout[row * EDIM + cg] = (v2 + bq[cg]) * 0.125f;   // 1/sqrt(64)
    else if (cg < 2 * EDIM)
        kout[row * EDIM + (cg - EDIM)] = v2;
    else
        vout[row * EDIM + (cg - 2 * EDIM)] = v2 + bv[cg - 2 * EDIM];
}

// ---------------------------------------------------------------------------
// Kernel 3a: split-K attention partial, DMA-staged K AND V.
// Identical to R6 except: K tile is DMA'd with NT cache policy (no L3
// allocation -> K stream stops thrashing/filling L3; V stays L3-resident).
// ---------------------------------------------------------------------------
__global__ __launch_bounds__(256) void attn_part(
    const float* __restrict__ q,       // [64][1280], pre-scaled
    const float* __restrict__ Kpast,   // [1280][448][64]
    const float* __restrict__ Vpast,
    const float* __restrict__ mask,    // [448]
    float* __restrict__ ctxbuf,        // [1280][7][64]
    float* __restrict__ msbuf)         // [1280][7][2]  (max, sum)
{
    __shared__ __align__(16) float kbuf[4096];   // 16 KB (reused for reductions)
    __shared__ __align__(16) float vbuf[4096];   // 16 KB

    const int chunk = blockIdx.x;          // 0..6
    const int bh    = blockIdx.y;          // 0..1279
    const int b  = bh / HDIM;
    const int hh = bh % HDIM;
    const int t  = threadIdx.x;
    const int w  = t >> 6;
    const int lane = t & 63;
    const int grp = t >> 4;                // 0..15
    const int dg  = t & 15;                // float4 slice of the 64-float row

    const float* Kt = Kpast + ((size_t)bh * PDIM + chunk * 64) * DDIM;
    const float* Vt = Vpast + ((size_t)bh * PDIM + chunk * 64) * DDIM;

    // ---- fire-and-forget DMA: K non-temporal, V default (L3-resident) ----
    dma_tile<2>(Kt, kbuf, w, lane);   // NT
    dma_tile<0>(Vt, vbuf, w, lane);

    const int j0 = chunk * 64 + grp;       // keys j0, j0+16, j0+32, j0+48
    const float4 qv = *reinterpret_cast<const float4*>(q + b * EDIM + hh * DDIM + dg * 4);
    const float mk0 = mask[j0], mk1 = mask[j0 + 16];
    const float mk2 = mask[j0 + 32], mk3 = mask[j0 + 48];

    __syncthreads();   // vmcnt(0)+lgkmcnt(0) drain + barrier: tiles resident

    // ---- scores from LDS K ----
    float4 k0 = *reinterpret_cast<const float4*>(kbuf + grp * DDIM + dg * 4);
    float4 k1 = *reinterpret_cast<const float4*>(kbuf + (grp + 16) * DDIM + dg * 4);
    float4 k2 = *reinterpret_cast<const float4*>(kbuf + (grp + 32) * DDIM + dg * 4);
    float4 k3 = *reinterpret_cast<const float4*>(kbuf + (grp + 48) * DDIM + dg * 4);
    float s0 = dot4(qv, k0), s1 = dot4(qv, k1), s2 = dot4(qv, k2), s3 = dot4(qv, k3);
#pragma unroll
    for (int off = 8; off; off >>= 1) {
        s0 += __shfl_xor(s0, off, 16);
        s1 += __shfl_xor(s1, off, 16);
        s2 += __shfl_xor(s2, off, 16);
        s3 += __shfl_xor(s3, off, 16);
    }
    s0 += mk0; s1 += mk1; s2 += mk2; s3 += mk3;

    // ---- wave max ----
    float m4 = fmaxf(fmaxf(s0, s1), fmaxf(s2, s3));
    m4 = fmaxf(m4, __shfl_xor(m4, 16, 64));
    m4 = fmaxf(m4, __shfl_xor(m4, 32, 64));

    __syncthreads();   // all waves done reading kbuf -> reusable as scratch
    float* redm = kbuf;                    // [4]
    float* reds = kbuf + 8;                // [4]
    float4* ctxp = reinterpret_cast<float4*>(kbuf + 16);   // [4][16]

    if (lane == 0) redm[w] = m4;
    __syncthreads();
    const float mx = fmaxf(fmaxf(redm[0], redm[1]), fmaxf(redm[2], redm[3]));

    // ---- exp, local sum, weighted-V from LDS ----
    float p0 = __expf(s0 - mx), p1 = __expf(s1 - mx);
    float p2 = __expf(s2 - mx), p3 = __expf(s3 - mx);
    float ls = p0 + p1 + p2 + p3;
    ls += __shfl_xor(ls, 16, 64);
    ls += __shfl_xor(ls, 32, 64);

    float4 v0 = *reinterpret_cast<const float4*>(vbuf + grp * DDIM + dg * 4);
    float4 v1 = *reinterpret_cast<const float4*>(vbuf + (grp + 16) * DDIM + dg * 4);
    float4 v2 = *reinterpret_cast<const float4*>(vbuf + (grp + 32) * DDIM + dg * 4);
    float4 v3 = *reinterpret_cast<const float4*>(vbuf + (grp + 48) * DDIM + dg * 4);

    float4 acc;
    acc.x = p0 * v0.x + p1 * v1.x + p2 * v2.x + p3 * v3.x;
    acc.y = p0 * v0.y + p1 * v1.y + p2 * v2.y + p3 * v3.y;
    acc.z = p0 * v0.z + p1 * v1.z + p2 * v2.z + p3 * v3.z;
    acc.w = p0 * v0.w + p1 * v1.w + p2 * v2.w + p3 * v3.w;
    acc.x += __shfl_xor(acc.x, 16, 64); acc.y += __shfl_xor(acc.y, 16, 64);
    acc.z += __shfl_xor(acc.z, 16, 64); acc.w += __shfl_xor(acc.w, 16, 64);
    acc.x += __shfl_xor(acc.x, 32, 64); acc.y += __shfl_xor(acc.y, 32, 64);
    acc.z += __shfl_xor(acc.z, 32, 64); acc.w += __shfl_xor(acc.w, 32, 64);

    if (lane == 0) reds[w] = ls;
    if (lane < 16) ctxp[w * 16 + lane] = acc;
    __syncthreads();

    if (t < 16) {
        float4 a0 = ctxp[t], a1 = ctxp[16 + t], a2 = ctxp[32 + t], a3 = ctxp[48 + t];
        float4 r;
        r.x = a0.x + a1.x + a2.x + a3.x;
        r.y = a0.y + a1.y + a2.y + a3.y;
        r.z = a0.z + a1.z + a2.z + a3.z;
        r.w = a0.w + a1.w + a2.w + a3.w;
        *reinterpret_cast<float4*>(ctxbuf + ((size_t)bh * KCHUNKS + chunk) * 64 + t * 4) = r;
    }
    if (t == 0) {
        msbuf[((size_t)bh * KCHUNKS + chunk) * 2 + 0] = mx;
        msbuf[((size_t)bh * KCHUNKS + chunk) * 2 + 1] = reds[0] + reds[1] + reds[2] + reds[3];
    }
}

// ---------------------------------------------------------------------------
// Kernel 3b: combine 7 chunk records + new key/value, online softmax merge.
// ---------------------------------------------------------------------------
__global__ __launch_bounds__(256) void attn_combine(
    const float* __restrict__ q,       // pre-scaled
    const float* __restrict__ knew,    // [64][1280]
    const float* __restrict__ vnew,
    const float* __restrict__ ctxbuf,
    const float* __restrict__ msbuf,
    float* __restrict__ merged)        // [64][1280]
{
    const int unit = blockIdx.x * 4 + (threadIdx.x >> 6);   // bh
    const int lane = threadIdx.x & 63;
    const int b  = unit / HDIM;
    const int hh = unit % HDIM;

    float mc[KCHUNKS], sc[KCHUNKS];
    float M = -3.4e38f;
#pragma unroll
    for (int c = 0; c < KCHUNKS; ++c) {
        mc[c] = msbuf[((size_t)unit * KCHUNKS + c) * 2 + 0];
        sc[c] = msbuf[((size_t)unit * KCHUNKS + c) * 2 + 1];
        M = fmaxf(M, mc[c]);
    }

    // new key score
    const int base = b * EDIM + hh * DDIM + lane;
    float sn = q[base] * knew[base];
#pragma unroll
    for (int off = 32; off; off >>= 1) sn += __shfl_xor(sn, off, 64);

    const float M2 = fmaxf(M, sn);
    const float pn = __expf(sn - M2);
    float S   = pn;
    float ctx = pn * vnew[base];
#pragma unroll
    for (int c = 0; c < KCHUNKS; ++c) {
        float e = __expf(mc[c] - M2);
        S   += sc[c] * e;
        ctx += e * ctxbuf[((size_t)unit * KCHUNKS + c) * 64 + lane];
    }
    merged[base] = ctx / S;
}

// ---------------------------------------------------------------------------
// Kernel 4: output projection, LDS-staged weights.
// ---------------------------------------------------------------------------
__global__ __launch_bounds__(256) void proj_out(
    const float* __restrict__ x,
    const float* __restrict__ Wo,
    float* __restrict__ partial)
{
    __shared__ float Wt[CTILE * ECHUNK];

    const int wave = threadIdx.x >> 6;
    const int lane = threadIdx.x & 63;
    const int colbase = blockIdx.x * CTILE;
    const int e0 = blockIdx.y * ECHUNK;

#pragma unroll
    for (int i = 0; i < 10; ++i) {
        int i4 = (i * 256 + threadIdx.x) * 4;
        int c  = i4 / ECHUNK;
        int e  = i4 - c * ECHUNK;
        *reinterpret_cast<float4*>(&Wt[i4]) =
            *reinterpret_cast<const float4*>(&Wo[(size_t)(colbase + c) * EDIM + e0 + e]);
    }
    __syncthreads();

    float acc[8];
#pragma unroll
    for (int c = 0; c < 8; ++c) acc[c] = 0.f;

    const float4* xp = reinterpret_cast<const float4*>(x + lane * EDIM + e0);
    const int c0 = wave * 8;
#pragma unroll 4
    for (int eg = 0; eg < ECHUNK / 4; ++eg) {
        float4 hv = xp[eg];
#pragma unroll
        for (int c = 0; c < 8; ++c) {
            float4 wv = *reinterpret_cast<const float4*>(&Wt[(c0 + c) * ECHUNK + eg * 4]);
            acc[c] += dot4(hv, wv);
        }
    }
#pragma unroll
    for (int c = 0; c < 8; ++c)
        partial[((size_t)blockIdx.y * EDIM + colbase + c0 + c) * 64 + lane] = acc[c];
}

// ---------------------------------------------------------------------------
// Kernel 5: reduce output-projection partials + bias -> d_out[0:81920]
// ---------------------------------------------------------------------------
__global__ __launch_bounds__(256) void reduce_out(
    const float* __restrict__ partial, const float* __restrict__ bo,
    float* __restrict__ out)
{
    __shared__ float tile[256];
    const int cg0 = blockIdx.x * 4;
    const int idx = cg0 * 64 + threadIdx.x;
    float v = partial[idx] + partial[81920 + idx]
            + partial[163840 + idx] + partial[245760 + idx];
    tile[threadIdx.x] = v;
    __syncthreads();
    const int row = threadIdx.x >> 2;
    const int c   = threadIdx.x & 3;
    const int cg  = cg0 + c;
    out[row * EDIM + cg] = tile[c * 64 + row] + bo[cg];
}

// ---------------------------------------------------------------------------
extern "C" void kernel_launch(void* const* d_in, const int* in_sizes, int n_in,
                              void* d_out, int out_size, void* d_ws, size_t ws_size,
                              hipStream_t stream)
{
    const float* h    = (const float*)d_in[0];
    const float* pk   = (const float*)d_in[1];
    const float* pv   = (const float*)d_in[2];
    const float* mask = (const float*)d_in[3];
    const float* Wq   = (const float*)d_in[4];
    const float* bq   = (const float*)d_in[5];
    const float* Wk   = (const float*)d_in[6];
    const float* Wv   = (const float*)d_in[7];
    const float* bv   = (const float*)d_in[8];
    const float* Wo   = (const float*)d_in[9];
    const float* bo   = (const float*)d_in[10];

    float* out  = (float*)d_out;            // [64][1280]
    float* kout = (float*)d_out + 81920;    // new_k
    float* vout = (float*)d_out + 163840;   // new_v

    float* ws    = (float*)d_ws;
    float* partP = ws;                        // 983040 floats (dead after reduce_proj)
    float* ctxb  = ws;                        // aliases partP: 1280*7*64 = 573440
    float* msb   = ws + 573440;               // 1280*7*2 = 17920 (still < 983040)
    float* qbuf  = ws + 983040;               // 81920
    float* mrg   = ws + 983040 + 81920;       // 81920
    float* partO = ws + 983040 + 163840;      // 327680

    proj_qkv<<<dim3(NCOL / CTILE, NCHUNK), 256, 0, stream>>>(h, Wq, Wk, Wv, partP);
    reduce_proj<<<dim3(NCOL / 4), 256, 0, stream>>>(partP, bq, bv, qbuf, kout, vout);
    attn_part<<<dim3(KCHUNKS, BDIM * HDIM), 256, 0, stream>>>(qbuf, pk, pv, mask, ctxb, msb);
    attn_combine<<<dim3(BDIM * HDIM / 4), 256, 0, stream>>>(qbuf, kout, vout, ctxb, msb, mrg);
    proj_out<<<dim3(EDIM / CTILE, NCHUNK), 256, 0, stream>>>(mrg, Wo, partO);
    reduce_out<<<dim3(EDIM / 4), 256, 0, stream>>>(partO, bo, out);
}